// Round 11
// baseline (505.172 us; speedup 1.0000x reference)
//
#include <hip/hip_runtime.h>

#define N_GRAPHS    8
#define EDGES_PER_G 2048
#define NN          8192
#define EE          16384
#define IN_DIM      10
#define EDGE_DIM    9
#define HID         64
#define OUT_DIM     3
#define TT          5
#define EPSN        1e-6f

typedef float f32x4 __attribute__((ext_vector_type(4)));
typedef short bf16x8s __attribute__((ext_vector_type(8)));

union BF8 { __bf16 h[8]; bf16x8s v; };

// async global->LDS, 16B per lane: lds dest MUST be wave-uniform (HW adds
// lane*16 itself); global src is per-lane. (m104/m108 — the r7 failure was a
// per-lane dest here.)
__device__ inline void gl_lds16(const unsigned short* g, unsigned short* l) {
  __builtin_amdgcn_global_load_lds(
      (const __attribute__((address_space(1))) unsigned int*)g,
      (__attribute__((address_space(3))) unsigned int*)l, 16, 0, 0);
}

// ------- edge MLP, 16 edges/block, 4 edges/wave (lane = channel) -----------------
// smem must hold >= 2*16*68 floats.
__device__ inline void edgemlp16(int e0, int tid,
    const float* __restrict__ ear, const float* __restrict__ meanb,
    const float* __restrict__ invstd,
    const float* __restrict__ w1, const float* __restrict__ b1,
    const float* __restrict__ w2, const float* __restrict__ b2,
    float* smem, float* __restrict__ h2T) {
  float (*sh)[68] = (float (*)[68])smem;             // [16][68] h1 staging
  float (*st)[68] = (float (*)[68])(smem + 16 * 68); // [16][68] h2 staging
  int g = tid >> 6, lane = tid & 63;
  int eb = e0 + g * 4;
  int gg = e0 >> 11;                       // 16-edge blocks never straddle graphs
  const float* mb = meanb + gg * EDGE_DIM;
  const float* is = invstd + gg * EDGE_DIM;
  float xn[4][EDGE_DIM];
#pragma unroll
  for (int k = 0; k < 4; ++k) {
    const float* er = ear + (size_t)(eb + k) * EDGE_DIM;
#pragma unroll
    for (int d = 0; d < EDGE_DIM; ++d) xn[k][d] = (er[d] - mb[d]) * is[d];
  }
  float a0 = b1[lane], a1 = a0, a2 = a0, a3 = a0;
#pragma unroll
  for (int d = 0; d < EDGE_DIM; ++d) {
    float w = w1[d * HID + lane];
    a0 += xn[0][d] * w; a1 += xn[1][d] * w;
    a2 += xn[2][d] * w; a3 += xn[3][d] * w;
  }
  sh[g * 4 + 0][lane] = fmaxf(a0, 0.f);
  sh[g * 4 + 1][lane] = fmaxf(a1, 0.f);
  sh[g * 4 + 2][lane] = fmaxf(a2, 0.f);
  sh[g * 4 + 3][lane] = fmaxf(a3, 0.f);
  __syncthreads();
  float o0 = b2[lane], o1 = o0, o2 = o0, o3 = o0;
#pragma unroll
  for (int h = 0; h < HID; ++h) {
    float w = w2[h * HID + lane];
    o0 += sh[g * 4 + 0][h] * w; o1 += sh[g * 4 + 1][h] * w;
    o2 += sh[g * 4 + 2][h] * w; o3 += sh[g * 4 + 3][h] * w;
  }
  st[g * 4 + 0][lane] = fmaxf(o0, 0.f);
  st[g * 4 + 1][lane] = fmaxf(o1, 0.f);
  st[g * 4 + 2][lane] = fmaxf(o2, 0.f);
  st[g * 4 + 3][lane] = fmaxf(o3, 0.f);
  __syncthreads();
  // transpose write: 16 consecutive threads write one channel's 16 edges (64B line)
  for (int i = tid; i < HID * 16; i += 256) {
    int c = i >> 4, eo = i & 15;
    h2T[(size_t)c * EE + e0 + eo] = st[eo][c];
  }
}

// ---------------- k_stats: per-graph edge stats (8 blocks) + zero degf (8) -------
__global__ __launch_bounds__(256) void k_stats(
    const float* __restrict__ ear, float* __restrict__ meanb,
    float* __restrict__ invstd, float* __restrict__ degf) {
  __shared__ float sw[4][2 * EDGE_DIM];
  int b = blockIdx.x;
  int g = threadIdx.x >> 6, lane = threadIdx.x & 63;
  if (b < N_GRAPHS) {
    int gg = b;
    float ls[EDGE_DIM], lq[EDGE_DIM];
#pragma unroll
    for (int d = 0; d < EDGE_DIM; ++d) { ls[d] = 0.f; lq[d] = 0.f; }
    for (int e = threadIdx.x; e < EDGES_PER_G; e += blockDim.x) {
      const float* row = ear + (size_t)(gg * EDGES_PER_G + e) * EDGE_DIM;
#pragma unroll
      for (int d = 0; d < EDGE_DIM; ++d) { float xv = row[d]; ls[d] += xv; lq[d] += xv * xv; }
    }
#pragma unroll
    for (int d = 0; d < EDGE_DIM; ++d) {
#pragma unroll
      for (int off = 32; off > 0; off >>= 1) {
        ls[d] += __shfl_down(ls[d], off);
        lq[d] += __shfl_down(lq[d], off);
      }
    }
    if (lane == 0) {
#pragma unroll
      for (int d = 0; d < EDGE_DIM; ++d) {
        sw[g][d] = ls[d];
        sw[g][EDGE_DIM + d] = lq[d];
      }
    }
    __syncthreads();
    if (threadIdx.x < EDGE_DIM) {
      int d = threadIdx.x;
      float s0 = sw[0][d] + sw[1][d] + sw[2][d] + sw[3][d];
      float q0 = sw[0][EDGE_DIM + d] + sw[1][EDGE_DIM + d] +
                 sw[2][EDGE_DIM + d] + sw[3][EDGE_DIM + d];
      float m  = s0 * (1.0f / EDGES_PER_G);
      float mq = q0 * (1.0f / EDGES_PER_G);
      float var = fmaxf(mq - m * m, 0.f);
      meanb[gg * EDGE_DIM + d]  = m;
      invstd[gg * EDGE_DIM + d] = 1.f / (sqrtf(var) + EPSN);
    }
  } else {
    int idx = (b - N_GRAPHS) * 256 + threadIdx.x;
    ((float4*)degf)[idx] = make_float4(0.f, 0.f, 0.f, 0.f);
  }
}

// -------- k_pre: em(layer0) | lift | bprep | deg-hist | zero-aggr ----------------
#define PRE_EM0   (EE / 16)
#define PRE_LIFT  (NN / 4)
#define PRE_BPREP 1024
#define PRE_DEG   (EE / 256)
#define PRE_ZAG   (NN * HID / 1024)
__global__ __launch_bounds__(256) void k_pre(
    const float* __restrict__ x,
    const float* __restrict__ lw1, const float* __restrict__ lb1,
    const float* __restrict__ lw2, const float* __restrict__ lb2,
    float* __restrict__ v,
    const float* __restrict__ kw3, const float* __restrict__ kb3,
    unsigned short* __restrict__ Bbf,
    const int* __restrict__ dst, float* __restrict__ degf,
    const float* __restrict__ ear, const float* __restrict__ meanb,
    const float* __restrict__ invstd, float* __restrict__ aggr,
    const float* __restrict__ w1, const float* __restrict__ b1,
    const float* __restrict__ w2, const float* __restrict__ b2,
    float* __restrict__ h2T0) {
  __shared__ float smem[2 * 16 * 68];
  int b = blockIdx.x;
  int g = threadIdx.x >> 6, lane = threadIdx.x & 63;
  if (b < PRE_EM0) {
    edgemlp16(b * 16, threadIdx.x, ear, meanb, invstd, w1, b1, w2, b2,
              smem, h2T0);
  } else if (b < PRE_EM0 + PRE_LIFT) {
    // ---- lift MLP ----
    float (*sh)[HID] = (float (*)[HID])smem;
    int n = (b - PRE_EM0) * 4 + g;
    const float* xr = x + n * IN_DIM;
    float a = lb1[lane];
#pragma unroll
    for (int d = 0; d < IN_DIM; ++d) a += xr[d] * lw1[d * HID + lane];
    sh[g][lane] = fmaxf(a, 0.f);
    __syncthreads();
    float o = lb2[lane];
#pragma unroll
    for (int h = 0; h < HID; ++h) o += sh[g][h] * lw2[h * HID + lane];
    v[n * HID + lane] = o;
  } else if (b < PRE_EM0 + PRE_LIFT + PRE_BPREP) {
    // ---- bprep: kw3 (+kb3 as row 64) -> bf16 fragment-major ----
    const int total = TT * 65 * 4096;
    for (int i = (b - (PRE_EM0 + PRE_LIFT)) * 256 + (int)threadIdx.x; i < total;
         i += PRE_BPREP * 256) {
      int xx   = i & 4095;
      int call = i >> 12;
      int t = call / 65;
      int c = call - t * 65;
      int sn = xx >> 9;              // s*4+nt
      int s  = sn >> 2, nt = sn & 3;
      int l9 = xx & 511;
      int ln = l9 >> 3, jj = l9 & 7;
      int nn15 = ln & 15, qq = ln >> 4;
      int x_in = (nt * 16 + nn15) * 64 + s * 32 + qq * 8 + jj;
      float val = (c < 64) ? kw3[(size_t)(t * 64 + c) * 4096 + x_in]
                           : kb3[(size_t)t * 4096 + x_in];
      union { __bf16 h; unsigned short s16; } u;
      u.h = (__bf16)val;
      Bbf[i] = u.s16;
    }
  } else if (b < PRE_EM0 + PRE_LIFT + PRE_BPREP + PRE_DEG) {
    // ---- deg histogram (degf zeroed in k_stats) ----
    int e = (b - (PRE_EM0 + PRE_LIFT + PRE_BPREP)) * 256 + threadIdx.x;
    atomicAdd(&degf[dst[e]], 1.f);
  } else {
    // ---- zero aggr (float4, 512 blocks) ----
    int idx = (b - (PRE_EM0 + PRE_LIFT + PRE_BPREP + PRE_DEG)) * 256 + threadIdx.x;
    ((float4*)aggr)[idx] = make_float4(0.f, 0.f, 0.f, 0.f);
  }
}

// ---------------- msg GEMM: B LDS-resident, barrier-free compute loop ------------
// Block = (kchunk of 8 channels, 256-edge group); grid 8x64 = 512 = 2 blocks/CU
// (64KB LDS). Stage the full 64KB B-chunk ONCE (wave-uniform dest chunks, the
// fix for r7's per-lane-dest bug), one vmcnt(0)+barrier, then the cc-loop runs
// with NO barriers and NO global B loads: per cc per wave = 8 ds_read_b128 +
// 4x(h float4) + 32 MFMA + 32 fold FMA, fully pipelineable by the compiler.
// This removes the per-iteration sync floor (~1100 cyc/iter) of the r6/r8/r10
// staged pipelines. kchunk 7 adds the bias row (h==1) straight from L2.
__global__ __launch_bounds__(256) void k_msg(const float* __restrict__ v,
    const float* __restrict__ h2T_r, const unsigned short* __restrict__ Bt,
    const int* __restrict__ src, const int* __restrict__ dst,
    float* __restrict__ aggr) {
  __shared__ unsigned short blds[8 * 4096];   // 64 KB: 8 channels x 8 KB
  int b = blockIdx.x;
  int kchunk = b & 7;
  int grp    = b >> 3;
  int w    = threadIdx.x >> 6;
  int lane = threadIdx.x & 63;
  int n15  = lane & 15;
  int q    = lane >> 4;
  int c0    = kchunk * 8;
  int ebase = grp * 256 + w * 64;

  // ---- stage B chunk: 64 x 1KB chunks; wave w stages chunks j*4+w ----
  // dest = blds + chunk*512 (WAVE-UNIFORM); src = + lane*8 (16B/lane x 64 = 1KB)
  const unsigned short* gB = Bt + (size_t)c0 * 4096;
#pragma unroll
  for (int j = 0; j < 16; ++j) {
    int chunk = j * 4 + w;
    gl_lds16(gB + (size_t)chunk * 512 + lane * 8, blds + (size_t)chunk * 512);
  }

  // ---- v gather + bf16 convert: 4 m-tiles = 64 edges per wave ----
  bf16x8s ubf[4][2];   // [m-tile][k-step s]
#pragma unroll
  for (int mt = 0; mt < 4; ++mt) {
    int e = ebase + mt * 16 + n15;
    const float4* vr = (const float4*)(v + (size_t)src[e] * HID);
    int f0 = q * 2;
#pragma unroll
    for (int s = 0; s < 2; ++s) {
      float4 pa = vr[s * 8 + f0], pb = vr[s * 8 + f0 + 1];
      BF8 u;
      u.h[0] = (__bf16)pa.x; u.h[1] = (__bf16)pa.y;
      u.h[2] = (__bf16)pa.z; u.h[3] = (__bf16)pa.w;
      u.h[4] = (__bf16)pb.x; u.h[5] = (__bf16)pb.y;
      u.h[6] = (__bf16)pb.z; u.h[7] = (__bf16)pb.w;
      ubf[mt][s] = u.v;
    }
  }

  f32x4 acc[4][4];
#pragma unroll
  for (int mt = 0; mt < 4; ++mt)
#pragma unroll
    for (int nt = 0; nt < 4; ++nt) acc[mt][nt] = (f32x4)0.0f;

  const float* hq = h2T_r + (size_t)c0 * EE + ebase + q * 4;

  // all stage + v loads complete; B visible to whole block. ONLY barrier.
  asm volatile("s_waitcnt vmcnt(0)" ::: "memory");
  __builtin_amdgcn_s_barrier();

  for (int cc = 0; cc < 8; ++cc) {
    const unsigned short* Bs = blds + cc * 4096 + lane * 8;
    bf16x8s bfr[2][4];
#pragma unroll
    for (int s = 0; s < 2; ++s)
#pragma unroll
      for (int nt = 0; nt < 4; ++nt)
        bfr[s][nt] = *(const bf16x8s*)(Bs + (s * 4 + nt) * 512);
    float4 h4[4];
#pragma unroll
    for (int mt = 0; mt < 4; ++mt)
      h4[mt] = *(const float4*)(hq + (size_t)cc * EE + mt * 16);
#pragma unroll
    for (int mt = 0; mt < 4; ++mt) {
      f32x4 tmp[4];
#pragma unroll
      for (int nt = 0; nt < 4; ++nt) {
        f32x4 t0 = __builtin_amdgcn_mfma_f32_16x16x32_bf16(
            ubf[mt][0], bfr[0][nt], (f32x4)0.0f, 0, 0, 0);
        tmp[nt] = __builtin_amdgcn_mfma_f32_16x16x32_bf16(
            ubf[mt][1], bfr[1][nt], t0, 0, 0, 0);
      }
      float4 hh = h4[mt];
#pragma unroll
      for (int nt = 0; nt < 4; ++nt) {
        acc[mt][nt][0] += hh.x * tmp[nt][0];
        acc[mt][nt][1] += hh.y * tmp[nt][1];
        acc[mt][nt][2] += hh.z * tmp[nt][2];
        acc[mt][nt][3] += hh.w * tmp[nt][3];
      }
    }
  }

  if (kchunk == 7) {
    // bias row c = 64 (h == 1): B straight from L2, accumulate into acc
    const unsigned short* Bc = Bt + (size_t)64 * 4096 + lane * 8;
    bf16x8s bfr[2][4];
#pragma unroll
    for (int s = 0; s < 2; ++s)
#pragma unroll
      for (int nt = 0; nt < 4; ++nt)
        bfr[s][nt] = *(const bf16x8s*)(Bc + (s * 4 + nt) * 512);
#pragma unroll
    for (int s = 0; s < 2; ++s)
#pragma unroll
      for (int mt = 0; mt < 4; ++mt)
#pragma unroll
        for (int nt = 0; nt < 4; ++nt)
          acc[mt][nt] = __builtin_amdgcn_mfma_f32_16x16x32_bf16(
              ubf[mt][s], bfr[s][nt], acc[mt][nt], 0, 0, 0);
  }

  // epilogue: C/D row = mt*16 + q*4 + r (edge), col = nt*16+n15; scatter by dst
#pragma unroll
  for (int mt = 0; mt < 4; ++mt) {
#pragma unroll
    for (int r = 0; r < 4; ++r) {
      int e = ebase + mt * 16 + q * 4 + r;
      int d = dst[e];
      float* ag = aggr + (size_t)d * HID;
#pragma unroll
      for (int nt = 0; nt < 4; ++nt)
        atomicAdd(ag + nt * 16 + n15, acc[mt][nt][r]);
    }
  }
}

// ------- update(t) [blocks 0..2047] + edge MLP for t+1 [blocks 2048..3071] -------
__global__ __launch_bounds__(256) void k_upd_em(
    float* __restrict__ v, const float* __restrict__ rw, const float* __restrict__ rb,
    float* __restrict__ aggr, const float* __restrict__ degf,
    const float* __restrict__ ear, const float* __restrict__ meanb,
    const float* __restrict__ invstd,
    const float* __restrict__ w1, const float* __restrict__ b1,
    const float* __restrict__ w2, const float* __restrict__ b2,
    float* __restrict__ h2T) {
  __shared__ float smem[2 * 16 * 68];
  int g = threadIdx.x >> 6, lane = threadIdx.x & 63;
  if (blockIdx.x < NN / 4) {
    float (*sh)[HID] = (float (*)[HID])smem;
    int n = blockIdx.x * 4 + g;
    int idx = n * HID + lane;
    sh[g][lane] = v[idx];
    __syncthreads();
    float inv = 1.f / fmaxf(degf[n], 1.f);
    float o = rb[lane] + aggr[idx] * inv;
    aggr[idx] = 0.f;                       // re-zero for next layer
#pragma unroll
    for (int h = 0; h < HID; ++h) o += sh[g][h] * rw[h * HID + lane];
    v[idx] = fmaxf(o, 0.f);
  } else {
    edgemlp16((blockIdx.x - NN / 4) * 16, threadIdx.x, ear, meanb, invstd,
              w1, b1, w2, b2, smem, h2T);
  }
}

// ------- final layer: update(T-1) + proj fused (per-node elementwise) ------------
__global__ __launch_bounds__(256) void k_upd_proj(
    const float* __restrict__ v, const float* __restrict__ rw,
    const float* __restrict__ rb,
    const float* __restrict__ aggr, const float* __restrict__ degf,
    const float* __restrict__ pw1, const float* __restrict__ pb1,
    const float* __restrict__ pw2, const float* __restrict__ pb2,
    float* __restrict__ out) {
  __shared__ float sh[4][HID];
  int g = threadIdx.x >> 6, lane = threadIdx.x & 63;
  int n = blockIdx.x * 4 + g;
  int idx = n * HID + lane;
  sh[g][lane] = v[idx];
  __syncthreads();
  float inv = 1.f / fmaxf(degf[n], 1.f);
  float o = rb[lane] + aggr[idx] * inv;
#pragma unroll
  for (int h = 0; h < HID; ++h) o += sh[g][h] * rw[h * HID + lane];
  float vn = fmaxf(o, 0.f);
  __syncthreads();
  sh[g][lane] = vn;                       // updated v row
  __syncthreads();
  float a = pb1[lane];
#pragma unroll
  for (int h = 0; h < HID; ++h) a += sh[g][h] * pw1[h * HID + lane];
  float h1 = fmaxf(a, 0.f);
  __syncthreads();
  sh[g][lane] = h1;
  __syncthreads();
  if (lane < OUT_DIM) {
    float oo = pb2[lane];
#pragma unroll
    for (int h = 0; h < HID; ++h) oo += sh[g][h] * pw2[h * OUT_DIM + lane];
    out[n * OUT_DIM + lane] = oo;
  }
}

extern "C" void kernel_launch(void* const* d_in, const int* in_sizes, int n_in,
                              void* d_out, int out_size, void* d_ws, size_t ws_size,
                              hipStream_t stream) {
  const float* x        = (const float*)d_in[0];
  const float* ear      = (const float*)d_in[1];
  const float* lift_w1  = (const float*)d_in[2];
  const float* lift_b1  = (const float*)d_in[3];
  const float* lift_w2  = (const float*)d_in[4];
  const float* lift_b2  = (const float*)d_in[5];
  const float* root_w   = (const float*)d_in[6];
  const float* root_b   = (const float*)d_in[7];
  const float* kw1      = (const float*)d_in[8];
  const float* kb1      = (const float*)d_in[9];
  const float* kw2      = (const float*)d_in[10];
  const float* kb2      = (const float*)d_in[11];
  const float* kw3      = (const float*)d_in[12];
  const float* kb3      = (const float*)d_in[13];
  const float* pw1      = (const float*)d_in[14];
  const float* pb1      = (const float*)d_in[15];
  const float* pw2      = (const float*)d_in[16];
  const float* pb2      = (const float*)d_in[17];
  const int* edge_index = (const int*)d_in[18];
  const int* src = edge_index;
  const int* dst = edge_index + EE;
  float* out = (float*)d_out;

  float* ws     = (float*)d_ws;
  float* aggr   = ws;                          // NN*HID
  float* degf   = aggr + NN * HID;             // NN
  float* h2Ta   = degf + NN;                   // HID*EE (transposed, buf A)
  float* h2Tb   = h2Ta + (size_t)HID * EE;     // HID*EE (buf B)
  float* vbuf   = h2Tb + (size_t)HID * EE;     // NN*HID
  float* meanb  = vbuf + NN * HID;             // 72
  float* invstd = meanb + 72;                  // 72
  unsigned short* Bbf = (unsigned short*)(invstd + 72);  // TT*65*4096 bf16

  k_stats<<<2 * N_GRAPHS, 256, 0, stream>>>(ear, meanb, invstd, degf);

  const int PRE_BLOCKS = PRE_EM0 + PRE_LIFT + PRE_BPREP + PRE_DEG + PRE_ZAG;
  k_pre<<<PRE_BLOCKS, 256, 0, stream>>>(
      x, lift_w1, lift_b1, lift_w2, lift_b2, vbuf, kw3, kb3, Bbf,
      dst, degf, ear, meanb, invstd, aggr,
      kw1, kb1, kw2, kb2, h2Ta);

  for (int t = 0; t < TT; ++t) {
    const float* hr = (t & 1) ? h2Tb : h2Ta;
    float*       hw = (t & 1) ? h2Ta : h2Tb;
    k_msg<<<512, 256, 0, stream>>>(
        vbuf, hr, Bbf + (size_t)t * 65 * 4096, src, dst, aggr);
    if (t < TT - 1) {
      int tt = t + 1;
      k_upd_em<<<NN / 4 + EE / 16, 256, 0, stream>>>(
          vbuf, root_w + (size_t)t * HID * HID, root_b + (size_t)t * HID,
          aggr, degf, ear, meanb, invstd,
          kw1 + (size_t)tt * EDGE_DIM * HID, kb1 + (size_t)tt * HID,
          kw2 + (size_t)tt * HID * HID, kb2 + (size_t)tt * HID, hw);
    } else {
      k_upd_proj<<<NN / 4, 256, 0, stream>>>(
          vbuf, root_w + (size_t)t * HID * HID, root_b + (size_t)t * HID,
          aggr, degf, pw1, pb1, pw2, pb2, out);
    }
  }
}

// Round 12
// 443.154 us; speedup vs baseline: 1.1399x; 1.1399x over previous
//
#include <hip/hip_runtime.h>

#define N_GRAPHS    8
#define EDGES_PER_G 2048
#define NN          8192
#define EE          16384
#define IN_DIM      10
#define EDGE_DIM    9
#define HID         64
#define OUT_DIM     3
#define TT          5
#define EPSN        1e-6f

typedef float f32x4 __attribute__((ext_vector_type(4)));
typedef short bf16x8s __attribute__((ext_vector_type(8)));

union BF8 { __bf16 h[8]; bf16x8s v; };

// async global->LDS, 16B per lane: lds dest MUST be wave-uniform (HW adds
// lane*16 itself); global src is per-lane. (m104/m108.)
__device__ inline void gl_lds16(const unsigned short* g, unsigned short* l) {
  __builtin_amdgcn_global_load_lds(
      (const __attribute__((address_space(1))) unsigned int*)g,
      (__attribute__((address_space(3))) unsigned int*)l, 16, 0, 0);
}

// ------- edge MLP, 16 edges/block, 4 edges/wave (lane = channel) -----------------
// smem must hold >= 2*16*68 floats.
__device__ inline void edgemlp16(int e0, int tid,
    const float* __restrict__ ear, const float* __restrict__ meanb,
    const float* __restrict__ invstd,
    const float* __restrict__ w1, const float* __restrict__ b1,
    const float* __restrict__ w2, const float* __restrict__ b2,
    float* smem, float* __restrict__ h2T) {
  float (*sh)[68] = (float (*)[68])smem;             // [16][68] h1 staging
  float (*st)[68] = (float (*)[68])(smem + 16 * 68); // [16][68] h2 staging
  int g = tid >> 6, lane = tid & 63;
  int eb = e0 + g * 4;
  int gg = e0 >> 11;                       // 16-edge blocks never straddle graphs
  const float* mb = meanb + gg * EDGE_DIM;
  const float* is = invstd + gg * EDGE_DIM;
  float xn[4][EDGE_DIM];
#pragma unroll
  for (int k = 0; k < 4; ++k) {
    const float* er = ear + (size_t)(eb + k) * EDGE_DIM;
#pragma unroll
    for (int d = 0; d < EDGE_DIM; ++d) xn[k][d] = (er[d] - mb[d]) * is[d];
  }
  float a0 = b1[lane], a1 = a0, a2 = a0, a3 = a0;
#pragma unroll
  for (int d = 0; d < EDGE_DIM; ++d) {
    float w = w1[d * HID + lane];
    a0 += xn[0][d] * w; a1 += xn[1][d] * w;
    a2 += xn[2][d] * w; a3 += xn[3][d] * w;
  }
  sh[g * 4 + 0][lane] = fmaxf(a0, 0.f);
  sh[g * 4 + 1][lane] = fmaxf(a1, 0.f);
  sh[g * 4 + 2][lane] = fmaxf(a2, 0.f);
  sh[g * 4 + 3][lane] = fmaxf(a3, 0.f);
  __syncthreads();
  float o0 = b2[lane], o1 = o0, o2 = o0, o3 = o0;
#pragma unroll
  for (int h = 0; h < HID; ++h) {
    float w = w2[h * HID + lane];
    o0 += sh[g * 4 + 0][h] * w; o1 += sh[g * 4 + 1][h] * w;
    o2 += sh[g * 4 + 2][h] * w; o3 += sh[g * 4 + 3][h] * w;
  }
  st[g * 4 + 0][lane] = fmaxf(o0, 0.f);
  st[g * 4 + 1][lane] = fmaxf(o1, 0.f);
  st[g * 4 + 2][lane] = fmaxf(o2, 0.f);
  st[g * 4 + 3][lane] = fmaxf(o3, 0.f);
  __syncthreads();
  // transpose write: 16 consecutive threads write one channel's 16 edges (64B line)
  for (int i = tid; i < HID * 16; i += 256) {
    int c = i >> 4, eo = i & 15;
    h2T[(size_t)c * EE + e0 + eo] = st[eo][c];
  }
}

// ---------------- k_stats: per-graph edge stats (8 blocks) + zero degf (8) -------
__global__ __launch_bounds__(256) void k_stats(
    const float* __restrict__ ear, float* __restrict__ meanb,
    float* __restrict__ invstd, float* __restrict__ degf) {
  __shared__ float sw[4][2 * EDGE_DIM];
  int b = blockIdx.x;
  int g = threadIdx.x >> 6, lane = threadIdx.x & 63;
  if (b < N_GRAPHS) {
    int gg = b;
    float ls[EDGE_DIM], lq[EDGE_DIM];
#pragma unroll
    for (int d = 0; d < EDGE_DIM; ++d) { ls[d] = 0.f; lq[d] = 0.f; }
    for (int e = threadIdx.x; e < EDGES_PER_G; e += blockDim.x) {
      const float* row = ear + (size_t)(gg * EDGES_PER_G + e) * EDGE_DIM;
#pragma unroll
      for (int d = 0; d < EDGE_DIM; ++d) { float xv = row[d]; ls[d] += xv; lq[d] += xv * xv; }
    }
#pragma unroll
    for (int d = 0; d < EDGE_DIM; ++d) {
#pragma unroll
      for (int off = 32; off > 0; off >>= 1) {
        ls[d] += __shfl_down(ls[d], off);
        lq[d] += __shfl_down(lq[d], off);
      }
    }
    if (lane == 0) {
#pragma unroll
      for (int d = 0; d < EDGE_DIM; ++d) {
        sw[g][d] = ls[d];
        sw[g][EDGE_DIM + d] = lq[d];
      }
    }
    __syncthreads();
    if (threadIdx.x < EDGE_DIM) {
      int d = threadIdx.x;
      float s0 = sw[0][d] + sw[1][d] + sw[2][d] + sw[3][d];
      float q0 = sw[0][EDGE_DIM + d] + sw[1][EDGE_DIM + d] +
                 sw[2][EDGE_DIM + d] + sw[3][EDGE_DIM + d];
      float m  = s0 * (1.0f / EDGES_PER_G);
      float mq = q0 * (1.0f / EDGES_PER_G);
      float var = fmaxf(mq - m * m, 0.f);
      meanb[gg * EDGE_DIM + d]  = m;
      invstd[gg * EDGE_DIM + d] = 1.f / (sqrtf(var) + EPSN);
    }
  } else {
    int idx = (b - N_GRAPHS) * 256 + threadIdx.x;
    ((float4*)degf)[idx] = make_float4(0.f, 0.f, 0.f, 0.f);
  }
}

// -------- k_pre: em(layer0) | lift | bprep | deg-hist | zero-aggr ----------------
#define PRE_EM0   (EE / 16)
#define PRE_LIFT  (NN / 4)
#define PRE_BPREP 1024
#define PRE_DEG   (EE / 256)
#define PRE_ZAG   (NN * HID / 1024)
__global__ __launch_bounds__(256) void k_pre(
    const float* __restrict__ x,
    const float* __restrict__ lw1, const float* __restrict__ lb1,
    const float* __restrict__ lw2, const float* __restrict__ lb2,
    float* __restrict__ v,
    const float* __restrict__ kw3, const float* __restrict__ kb3,
    unsigned short* __restrict__ Bbf,
    const int* __restrict__ dst, float* __restrict__ degf,
    const float* __restrict__ ear, const float* __restrict__ meanb,
    const float* __restrict__ invstd, float* __restrict__ aggr,
    const float* __restrict__ w1, const float* __restrict__ b1,
    const float* __restrict__ w2, const float* __restrict__ b2,
    float* __restrict__ h2T0) {
  __shared__ float smem[2 * 16 * 68];
  int b = blockIdx.x;
  int g = threadIdx.x >> 6, lane = threadIdx.x & 63;
  if (b < PRE_EM0) {
    edgemlp16(b * 16, threadIdx.x, ear, meanb, invstd, w1, b1, w2, b2,
              smem, h2T0);
  } else if (b < PRE_EM0 + PRE_LIFT) {
    // ---- lift MLP ----
    float (*sh)[HID] = (float (*)[HID])smem;
    int n = (b - PRE_EM0) * 4 + g;
    const float* xr = x + n * IN_DIM;
    float a = lb1[lane];
#pragma unroll
    for (int d = 0; d < IN_DIM; ++d) a += xr[d] * lw1[d * HID + lane];
    sh[g][lane] = fmaxf(a, 0.f);
    __syncthreads();
    float o = lb2[lane];
#pragma unroll
    for (int h = 0; h < HID; ++h) o += sh[g][h] * lw2[h * HID + lane];
    v[n * HID + lane] = o;
  } else if (b < PRE_EM0 + PRE_LIFT + PRE_BPREP) {
    // ---- bprep: kw3 (+kb3 as row 64) -> bf16 fragment-major ----
    const int total = TT * 65 * 4096;
    for (int i = (b - (PRE_EM0 + PRE_LIFT)) * 256 + (int)threadIdx.x; i < total;
         i += PRE_BPREP * 256) {
      int xx   = i & 4095;
      int call = i >> 12;
      int t = call / 65;
      int c = call - t * 65;
      int sn = xx >> 9;              // s*4+nt
      int s  = sn >> 2, nt = sn & 3;
      int l9 = xx & 511;
      int ln = l9 >> 3, jj = l9 & 7;
      int nn15 = ln & 15, qq = ln >> 4;
      int x_in = (nt * 16 + nn15) * 64 + s * 32 + qq * 8 + jj;
      float val = (c < 64) ? kw3[(size_t)(t * 64 + c) * 4096 + x_in]
                           : kb3[(size_t)t * 4096 + x_in];
      union { __bf16 h; unsigned short s16; } u;
      u.h = (__bf16)val;
      Bbf[i] = u.s16;
    }
  } else if (b < PRE_EM0 + PRE_LIFT + PRE_BPREP + PRE_DEG) {
    // ---- deg histogram (degf zeroed in k_stats) ----
    int e = (b - (PRE_EM0 + PRE_LIFT + PRE_BPREP)) * 256 + threadIdx.x;
    atomicAdd(&degf[dst[e]], 1.f);
  } else {
    // ---- zero aggr (float4, 512 blocks) ----
    int idx = (b - (PRE_EM0 + PRE_LIFT + PRE_BPREP + PRE_DEG)) * 256 + threadIdx.x;
    ((float4*)aggr)[idx] = make_float4(0.f, 0.f, 0.f, 0.f);
  }
}

// ------- msg GEMM (r10 pipeline, 8-way channel split for shorter waves) ----------
// Blocks 0..2047: kchunk = b&7 (8 channels), 64 edges (4 waves x 16 edges, mt=1).
// vs r10: cc-loop halves (8-9 iters) at CONSTANT total B L2 traffic (2048 x
// 64KB = r10's 1024 x 128KB); per-block shared-B L1 reuse preserved (the r4
// mistake avoided). Wave-life ~halves; wave count doubles; LDS 24KB -> up to
// 6 blocks/CU. Atomic partials 8/edge (8.4M lane-ops; 4x swings proven free).
// Blocks 2048..2048+nEm: edge MLP for layer t+1 into h2T_w (TLP filler).
__global__ __launch_bounds__(256) void k_msg(const float* __restrict__ v,
    const float* __restrict__ h2T_r, const unsigned short* __restrict__ Bt,
    const int* __restrict__ src, const int* __restrict__ dst,
    float* __restrict__ aggr, int nEm,
    const float* __restrict__ ear, const float* __restrict__ meanb,
    const float* __restrict__ invstd,
    const float* __restrict__ w1, const float* __restrict__ b1,
    const float* __restrict__ w2, const float* __restrict__ b2,
    float* __restrict__ h2T_w) {
  __shared__ unsigned short bstage[3][4096];   // 3 x 8KB rotating B tiles
  int b = blockIdx.x;
  if (b < 2048) {
    int kchunk = b & 7;
    int ebb    = (b >> 3) * 64;
    int w    = threadIdx.x >> 6;
    int lane = threadIdx.x & 63;
    int n15  = lane & 15;
    int q    = lane >> 4;
    int ebase = ebb + w * 16;

    // load v rows, convert to bf16 A-fragments once (one 16-edge m-tile)
    bf16x8s ubf[2];   // [k-step s]
    {
      int e = ebase + n15;
      const float4* vr = (const float4*)(v + (size_t)src[e] * HID);
      int f0 = q * 2;
#pragma unroll
      for (int s = 0; s < 2; ++s) {
        float4 pa = vr[s * 8 + f0], pb = vr[s * 8 + f0 + 1];
        BF8 u;
        u.h[0] = (__bf16)pa.x; u.h[1] = (__bf16)pa.y;
        u.h[2] = (__bf16)pa.z; u.h[3] = (__bf16)pa.w;
        u.h[4] = (__bf16)pb.x; u.h[5] = (__bf16)pb.y;
        u.h[6] = (__bf16)pb.z; u.h[7] = (__bf16)pb.w;
        ubf[s] = u.v;
      }
    }

    f32x4 acc[4];
#pragma unroll
    for (int nt = 0; nt < 4; ++nt) acc[nt] = (f32x4)0.0f;

    int c0 = kchunk * 8;
    const float* hq = h2T_r + (size_t)c0 * EE + ebase + q * 4;
    const int NCC = (kchunk == 7) ? 9 : 8;   // tile 8 = bias row (uniform)

    // stage tile cc into bstage[cc%3]: wave-uniform LDS dest, per-lane global src
    auto stage = [&](int cc) {
      const unsigned short* gt = (cc < 8)
          ? Bt + (size_t)(c0 + cc) * 4096
          : Bt + (size_t)64 * 4096;
      const unsigned short* gsrc = gt + w * 1024 + lane * 8;
      unsigned short* ldst = &bstage[cc % 3][w * 1024];
      gl_lds16(gsrc, ldst);
      gl_lds16(gsrc + 512, ldst + 512);
    };

    stage(0);
    stage(1);

    for (int cc = 0; cc < NCC; ++cc) {
      // stage(cc) complete when <=2 of my loads outstanding (only newer stages)
      asm volatile("s_waitcnt vmcnt(2)" ::: "memory");
      __builtin_amdgcn_s_barrier();
      // h row for THIS tile: issue before the stage so its consumption does
      // not drain the younger stage loads (vmcnt FIFO).
      float4 h4;
      if (cc < 8) h4 = *(const float4*)(hq + (size_t)cc * EE);
      __builtin_amdgcn_sched_barrier(0);
      if (cc + 2 < NCC) stage(cc + 2);
      __builtin_amdgcn_sched_barrier(0);

      const unsigned short* Bs = &bstage[cc % 3][lane * 8];
      bf16x8s bfr[2][4];
#pragma unroll
      for (int s = 0; s < 2; ++s)
#pragma unroll
        for (int nt = 0; nt < 4; ++nt)
          bfr[s][nt] = *(const bf16x8s*)(Bs + (s * 4 + nt) * 512);
      if (cc < 8) {
        f32x4 tmp[4];
#pragma unroll
        for (int nt = 0; nt < 4; ++nt) {
          f32x4 t0 = __builtin_amdgcn_mfma_f32_16x16x32_bf16(
              ubf[0], bfr[0][nt], (f32x4)0.0f, 0, 0, 0);
          tmp[nt] = __builtin_amdgcn_mfma_f32_16x16x32_bf16(
              ubf[1], bfr[1][nt], t0, 0, 0, 0);
        }
#pragma unroll
        for (int nt = 0; nt < 4; ++nt) {
          acc[nt][0] += h4.x * tmp[nt][0];
          acc[nt][1] += h4.y * tmp[nt][1];
          acc[nt][2] += h4.z * tmp[nt][2];
          acc[nt][3] += h4.w * tmp[nt][3];
        }
      } else {
        // bias row c = 64 (h == 1): accumulate directly, A-fragment is ubf
#pragma unroll
        for (int s = 0; s < 2; ++s)
#pragma unroll
          for (int nt = 0; nt < 4; ++nt)
            acc[nt] = __builtin_amdgcn_mfma_f32_16x16x32_bf16(
                ubf[s], bfr[s][nt], acc[nt], 0, 0, 0);
      }
    }

    // epilogue: C/D row = q*4+r (edge), col = n15; scatter-add by dst
#pragma unroll
    for (int r = 0; r < 4; ++r) {
      int e = ebase + q * 4 + r;
      int d = dst[e];
      float* ag = aggr + (size_t)d * HID;
#pragma unroll
      for (int nt = 0; nt < 4; ++nt)
        atomicAdd(ag + nt * 16 + n15, acc[nt][r]);
    }
  } else if (b < 2048 + nEm) {
    // ---- edge MLP for NEXT layer, overlapped with MFMA blocks ----
    edgemlp16((b - 2048) * 16, threadIdx.x, ear, meanb, invstd,
              w1, b1, w2, b2, (float*)bstage, h2T_w);
  }
}

// ------- pure update(t) ----------------------------------------------------------
__global__ __launch_bounds__(256) void k_upd(
    float* __restrict__ v, const float* __restrict__ rw, const float* __restrict__ rb,
    float* __restrict__ aggr, const float* __restrict__ degf) {
  __shared__ float sh[4][HID];
  int g = threadIdx.x >> 6, lane = threadIdx.x & 63;
  int n = blockIdx.x * 4 + g;
  int idx = n * HID + lane;
  sh[g][lane] = v[idx];
  __syncthreads();
  float inv = 1.f / fmaxf(degf[n], 1.f);
  float o = rb[lane] + aggr[idx] * inv;
  aggr[idx] = 0.f;                       // re-zero for next layer
#pragma unroll
  for (int h = 0; h < HID; ++h) o += sh[g][h] * rw[h * HID + lane];
  v[idx] = fmaxf(o, 0.f);
}

// ------- final layer: update(T-1) + proj fused (per-node elementwise) ------------
__global__ __launch_bounds__(256) void k_upd_proj(
    const float* __restrict__ v, const float* __restrict__ rw,
    const float* __restrict__ rb,
    const float* __restrict__ aggr, const float* __restrict__ degf,
    const float* __restrict__ pw1, const float* __restrict__ pb1,
    const float* __restrict__ pw2, const float* __restrict__ pb2,
    float* __restrict__ out) {
  __shared__ float sh[4][HID];
  int g = threadIdx.x >> 6, lane = threadIdx.x & 63;
  int n = blockIdx.x * 4 + g;
  int idx = n * HID + lane;
  sh[g][lane] = v[idx];
  __syncthreads();
  float inv = 1.f / fmaxf(degf[n], 1.f);
  float o = rb[lane] + aggr[idx] * inv;
#pragma unroll
  for (int h = 0; h < HID; ++h) o += sh[g][h] * rw[h * HID + lane];
  float vn = fmaxf(o, 0.f);
  __syncthreads();
  sh[g][lane] = vn;                       // updated v row
  __syncthreads();
  float a = pb1[lane];
#pragma unroll
  for (int h = 0; h < HID; ++h) a += sh[g][h] * pw1[h * HID + lane];
  float h1 = fmaxf(a, 0.f);
  __syncthreads();
  sh[g][lane] = h1;
  __syncthreads();
  if (lane < OUT_DIM) {
    float oo = pb2[lane];
#pragma unroll
    for (int h = 0; h < HID; ++h) oo += sh[g][h] * pw2[h * OUT_DIM + lane];
    out[n * OUT_DIM + lane] = oo;
  }
}

extern "C" void kernel_launch(void* const* d_in, const int* in_sizes, int n_in,
                              void* d_out, int out_size, void* d_ws, size_t ws_size,
                              hipStream_t stream) {
  const float* x        = (const float*)d_in[0];
  const float* ear      = (const float*)d_in[1];
  const float* lift_w1  = (const float*)d_in[2];
  const float* lift_b1  = (const float*)d_in[3];
  const float* lift_w2  = (const float*)d_in[4];
  const float* lift_b2  = (const float*)d_in[5];
  const float* root_w   = (const float*)d_in[6];
  const float* root_b   = (const float*)d_in[7];
  const float* kw1      = (const float*)d_in[8];
  const float* kb1      = (const float*)d_in[9];
  const float* kw2      = (const float*)d_in[10];
  const float* kb2      = (const float*)d_in[11];
  const float* kw3      = (const float*)d_in[12];
  const float* kb3      = (const float*)d_in[13];
  const float* pw1      = (const float*)d_in[14];
  const float* pb1      = (const float*)d_in[15];
  const float* pw2      = (const float*)d_in[16];
  const float* pb2      = (const float*)d_in[17];
  const int* edge_index = (const int*)d_in[18];
  const int* src = edge_index;
  const int* dst = edge_index + EE;
  float* out = (float*)d_out;

  float* ws     = (float*)d_ws;
  float* aggr   = ws;                          // NN*HID
  float* degf   = aggr + NN * HID;             // NN
  float* h2Ta   = degf + NN;                   // HID*EE (transposed, buf A)
  float* h2Tb   = h2Ta + (size_t)HID * EE;     // HID*EE (buf B)
  float* vbuf   = h2Tb + (size_t)HID * EE;     // NN*HID
  float* meanb  = vbuf + NN * HID;             // 72
  float* invstd = meanb + 72;                  // 72
  unsigned short* Bbf = (unsigned short*)(invstd + 72);  // TT*65*4096 bf16

  k_stats<<<2 * N_GRAPHS, 256, 0, stream>>>(ear, meanb, invstd, degf);

  const int PRE_BLOCKS = PRE_EM0 + PRE_LIFT + PRE_BPREP + PRE_DEG + PRE_ZAG;
  k_pre<<<PRE_BLOCKS, 256, 0, stream>>>(
      x, lift_w1, lift_b1, lift_w2, lift_b2, vbuf, kw3, kb3, Bbf,
      dst, degf, ear, meanb, invstd, aggr,
      kw1, kb1, kw2, kb2, h2Ta);

  for (int t = 0; t < TT; ++t) {
    const float* hr = (t & 1) ? h2Tb : h2Ta;
    float*       hw = (t & 1) ? h2Ta : h2Tb;
    int nEm = (t < TT - 1) ? EE / 16 : 0;
    int tt  = (t < TT - 1) ? t + 1 : t;    // em weights for next layer
    k_msg<<<2048 + nEm, 256, 0, stream>>>(
        vbuf, hr, Bbf + (size_t)t * 65 * 4096, src, dst, aggr, nEm,
        ear, meanb, invstd,
        kw1 + (size_t)tt * EDGE_DIM * HID, kb1 + (size_t)tt * HID,
        kw2 + (size_t)tt * HID * HID, kb2 + (size_t)tt * HID, hw);
    if (t < TT - 1) {
      k_upd<<<NN / 4, 256, 0, stream>>>(
          vbuf, root_w + (size_t)t * HID * HID, root_b + (size_t)t * HID,
          aggr, degf);
    } else {
      k_upd_proj<<<NN / 4, 256, 0, stream>>>(
          vbuf, root_w + (size_t)t * HID * HID, root_b + (size_t)t * HID,
          aggr, degf, pw1, pb1, pw2, pb2, out);
    }
  }
}

// Round 13
// 324.152 us; speedup vs baseline: 1.5584x; 1.3671x over previous
//
#include <hip/hip_runtime.h>

#define N_GRAPHS    8
#define EDGES_PER_G 2048
#define NN          8192
#define EE          16384
#define IN_DIM      10
#define EDGE_DIM    9
#define HID         64
#define OUT_DIM     3
#define TT          5
#define EPSN        1e-6f

typedef float f32x4 __attribute__((ext_vector_type(4)));
typedef short bf16x8s __attribute__((ext_vector_type(8)));

union BF8 { __bf16 h[8]; bf16x8s v; };

// async global->LDS, 16B per lane: lds dest MUST be wave-uniform (HW adds
// lane*16 itself); global src is per-lane. (m104/m108.)
__device__ inline void gl_lds16(const unsigned short* g, unsigned short* l) {
  __builtin_amdgcn_global_load_lds(
      (const __attribute__((address_space(1))) unsigned int*)g,
      (__attribute__((address_space(3))) unsigned int*)l, 16, 0, 0);
}

// ------- edge MLP, 16 edges/block, 4 edges/wave (lane = channel) -----------------
__device__ inline void edgemlp16(int e0, int tid,
    const float* __restrict__ ear, const float* __restrict__ meanb,
    const float* __restrict__ invstd,
    const float* __restrict__ w1, const float* __restrict__ b1,
    const float* __restrict__ w2, const float* __restrict__ b2,
    float* smem, float* __restrict__ h2T) {
  float (*sh)[68] = (float (*)[68])smem;             // [16][68] h1 staging
  float (*st)[68] = (float (*)[68])(smem + 16 * 68); // [16][68] h2 staging
  int g = tid >> 6, lane = tid & 63;
  int eb = e0 + g * 4;
  int gg = e0 >> 11;                       // 16-edge blocks never straddle graphs
  const float* mb = meanb + gg * EDGE_DIM;
  const float* is = invstd + gg * EDGE_DIM;
  float xn[4][EDGE_DIM];
#pragma unroll
  for (int k = 0; k < 4; ++k) {
    const float* er = ear + (size_t)(eb + k) * EDGE_DIM;
#pragma unroll
    for (int d = 0; d < EDGE_DIM; ++d) xn[k][d] = (er[d] - mb[d]) * is[d];
  }
  float a0 = b1[lane], a1 = a0, a2 = a0, a3 = a0;
#pragma unroll
  for (int d = 0; d < EDGE_DIM; ++d) {
    float w = w1[d * HID + lane];
    a0 += xn[0][d] * w; a1 += xn[1][d] * w;
    a2 += xn[2][d] * w; a3 += xn[3][d] * w;
  }
  sh[g * 4 + 0][lane] = fmaxf(a0, 0.f);
  sh[g * 4 + 1][lane] = fmaxf(a1, 0.f);
  sh[g * 4 + 2][lane] = fmaxf(a2, 0.f);
  sh[g * 4 + 3][lane] = fmaxf(a3, 0.f);
  __syncthreads();
  float o0 = b2[lane], o1 = o0, o2 = o0, o3 = o0;
#pragma unroll
  for (int h = 0; h < HID; ++h) {
    float w = w2[h * HID + lane];
    o0 += sh[g * 4 + 0][h] * w; o1 += sh[g * 4 + 1][h] * w;
    o2 += sh[g * 4 + 2][h] * w; o3 += sh[g * 4 + 3][h] * w;
  }
  st[g * 4 + 0][lane] = fmaxf(o0, 0.f);
  st[g * 4 + 1][lane] = fmaxf(o1, 0.f);
  st[g * 4 + 2][lane] = fmaxf(o2, 0.f);
  st[g * 4 + 3][lane] = fmaxf(o3, 0.f);
  __syncthreads();
  // transpose write: 16 consecutive threads write one channel's 16 edges (64B line)
  for (int i = tid; i < HID * 16; i += 256) {
    int c = i >> 4, eo = i & 15;
    h2T[(size_t)c * EE + e0 + eo] = st[eo][c];
  }
}

// ---------------- k_stats: per-graph edge stats (8 blocks) + zero degf (8) -------
__global__ __launch_bounds__(256) void k_stats(
    const float* __restrict__ ear, float* __restrict__ meanb,
    float* __restrict__ invstd, float* __restrict__ degf) {
  __shared__ float sw[4][2 * EDGE_DIM];
  int b = blockIdx.x;
  int g = threadIdx.x >> 6, lane = threadIdx.x & 63;
  if (b < N_GRAPHS) {
    int gg = b;
    float ls[EDGE_DIM], lq[EDGE_DIM];
#pragma unroll
    for (int d = 0; d < EDGE_DIM; ++d) { ls[d] = 0.f; lq[d] = 0.f; }
    for (int e = threadIdx.x; e < EDGES_PER_G; e += blockDim.x) {
      const float* row = ear + (size_t)(gg * EDGES_PER_G + e) * EDGE_DIM;
#pragma unroll
      for (int d = 0; d < EDGE_DIM; ++d) { float xv = row[d]; ls[d] += xv; lq[d] += xv * xv; }
    }
#pragma unroll
    for (int d = 0; d < EDGE_DIM; ++d) {
#pragma unroll
      for (int off = 32; off > 0; off >>= 1) {
        ls[d] += __shfl_down(ls[d], off);
        lq[d] += __shfl_down(lq[d], off);
      }
    }
    if (lane == 0) {
#pragma unroll
      for (int d = 0; d < EDGE_DIM; ++d) {
        sw[g][d] = ls[d];
        sw[g][EDGE_DIM + d] = lq[d];
      }
    }
    __syncthreads();
    if (threadIdx.x < EDGE_DIM) {
      int d = threadIdx.x;
      float s0 = sw[0][d] + sw[1][d] + sw[2][d] + sw[3][d];
      float q0 = sw[0][EDGE_DIM + d] + sw[1][EDGE_DIM + d] +
                 sw[2][EDGE_DIM + d] + sw[3][EDGE_DIM + d];
      float m  = s0 * (1.0f / EDGES_PER_G);
      float mq = q0 * (1.0f / EDGES_PER_G);
      float var = fmaxf(mq - m * m, 0.f);
      meanb[gg * EDGE_DIM + d]  = m;
      invstd[gg * EDGE_DIM + d] = 1.f / (sqrtf(var) + EPSN);
    }
  } else {
    int idx = (b - N_GRAPHS) * 256 + threadIdx.x;
    ((float4*)degf)[idx] = make_float4(0.f, 0.f, 0.f, 0.f);
  }
}

// -------- k_pre: em(layer0) | lift | bprep | deg-hist ---------------------------
#define PRE_EM0   (EE / 16)
#define PRE_LIFT  (NN / 4)
#define PRE_BPREP 1024
#define PRE_DEG   (EE / 256)
__global__ __launch_bounds__(256) void k_pre(
    const float* __restrict__ x,
    const float* __restrict__ lw1, const float* __restrict__ lb1,
    const float* __restrict__ lw2, const float* __restrict__ lb2,
    float* __restrict__ v,
    const float* __restrict__ kw3, const float* __restrict__ kb3,
    unsigned short* __restrict__ Bbf,
    const int* __restrict__ dst, float* __restrict__ degf,
    const float* __restrict__ ear, const float* __restrict__ meanb,
    const float* __restrict__ invstd,
    const float* __restrict__ w1, const float* __restrict__ b1,
    const float* __restrict__ w2, const float* __restrict__ b2,
    float* __restrict__ h2T0) {
  __shared__ float smem[2 * 16 * 68];
  int b = blockIdx.x;
  int g = threadIdx.x >> 6, lane = threadIdx.x & 63;
  if (b < PRE_EM0) {
    edgemlp16(b * 16, threadIdx.x, ear, meanb, invstd, w1, b1, w2, b2,
              smem, h2T0);
  } else if (b < PRE_EM0 + PRE_LIFT) {
    // ---- lift MLP ----
    float (*sh)[HID] = (float (*)[HID])smem;
    int n = (b - PRE_EM0) * 4 + g;
    const float* xr = x + n * IN_DIM;
    float a = lb1[lane];
#pragma unroll
    for (int d = 0; d < IN_DIM; ++d) a += xr[d] * lw1[d * HID + lane];
    sh[g][lane] = fmaxf(a, 0.f);
    __syncthreads();
    float o = lb2[lane];
#pragma unroll
    for (int h = 0; h < HID; ++h) o += sh[g][h] * lw2[h * HID + lane];
    v[n * HID + lane] = o;
  } else if (b < PRE_EM0 + PRE_LIFT + PRE_BPREP) {
    // ---- bprep: kw3 (+kb3 as row 64) -> bf16 fragment-major ----
    const int total = TT * 65 * 4096;
    for (int i = (b - (PRE_EM0 + PRE_LIFT)) * 256 + (int)threadIdx.x; i < total;
         i += PRE_BPREP * 256) {
      int xx   = i & 4095;
      int call = i >> 12;
      int t = call / 65;
      int c = call - t * 65;
      int sn = xx >> 9;              // s*4+nt
      int s  = sn >> 2, nt = sn & 3;
      int l9 = xx & 511;
      int ln = l9 >> 3, jj = l9 & 7;
      int nn15 = ln & 15, qq = ln >> 4;
      int x_in = (nt * 16 + nn15) * 64 + s * 32 + qq * 8 + jj;
      float val = (c < 64) ? kw3[(size_t)(t * 64 + c) * 4096 + x_in]
                           : kb3[(size_t)t * 4096 + x_in];
      union { __bf16 h; unsigned short s16; } u;
      u.h = (__bf16)val;
      Bbf[i] = u.s16;
    }
  } else {
    // ---- deg histogram (degf zeroed in k_stats) ----
    int e = (b - (PRE_EM0 + PRE_LIFT + PRE_BPREP)) * 256 + threadIdx.x;
    atomicAdd(&degf[dst[e]], 1.f);
  }
}

// ------- k_csr1: prefix-sum of degrees -> rowptr, cur (one 256-thread block) -----
__global__ __launch_bounds__(256) void k_csr1(const float* __restrict__ degf,
    int* __restrict__ rowptr, int* __restrict__ cur) {
  __shared__ int ps[256];
  int tid = threadIdx.x;
  int base = tid * 32;
  int loc[32];
  int s = 0;
#pragma unroll
  for (int k = 0; k < 32; ++k) { loc[k] = s; s += (int)degf[base + k]; }
  ps[tid] = s;
  __syncthreads();
  if (tid == 0) {
    int a = 0;
    for (int i = 0; i < 256; ++i) { int t = ps[i]; ps[i] = a; a += t; }
    rowptr[NN] = a;                       // == EE
  }
  __syncthreads();
  int off = ps[tid];
#pragma unroll
  for (int k = 0; k < 32; ++k) {
    rowptr[base + k] = off + loc[k];
    cur[base + k]    = off + loc[k];
  }
}

// ------- k_csr2: scatter edge ids into dst-sorted order (16K one-time atomics) ---
__global__ __launch_bounds__(256) void k_csr2(const int* __restrict__ dst,
    int* __restrict__ cur, int* __restrict__ ecsr) {
  int e = blockIdx.x * 256 + threadIdx.x;
  int d = dst[e];
  int pos = atomicAdd(&cur[d], 1);
  ecsr[pos] = e;
}

// ------- msg GEMM (r10 pipeline; epilogue = PLAIN STORES, no atomics) ------------
// Blocks 0..1023: kchunk = b&3 (16 channels), 64 edges (4 waves x 16 edges).
// Identical math/staging to the 334us r10 kernel. ONLY change: the per-edge
// 64-wide partial is plain-stored to msgbuf[kc][e][c] (fire-and-forget,
// coalesced, every slot rewritten every layer) instead of 16 memory-side
// atomic RMWs per lane (r5/r12 WRITE_SIZE evidence: device atomics bypass the
// non-coherent L2s and drain at the coherence point -> per-wave fixed cost).
// Blocks 1024..1024+nEm: edge MLP for layer t+1 into h2T_w.
__global__ __launch_bounds__(256) void k_msg(const float* __restrict__ v,
    const float* __restrict__ h2T_r, const unsigned short* __restrict__ Bt,
    const int* __restrict__ src,
    float* __restrict__ msgbuf, int nEm,
    const float* __restrict__ ear, const float* __restrict__ meanb,
    const float* __restrict__ invstd,
    const float* __restrict__ w1, const float* __restrict__ b1,
    const float* __restrict__ w2, const float* __restrict__ b2,
    float* __restrict__ h2T_w) {
  __shared__ unsigned short bstage[3][4096];   // 3 x 8KB rotating B tiles
  int b = blockIdx.x;
  if (b < 1024) {
    int kchunk = b & 3;
    int ebb    = (b >> 2) * 64;
    int w    = threadIdx.x >> 6;
    int lane = threadIdx.x & 63;
    int n15  = lane & 15;
    int q    = lane >> 4;
    int ebase = ebb + w * 16;

    // load v rows, convert to bf16 A-fragments once (one 16-edge m-tile)
    bf16x8s ubf[2];   // [k-step s]
    {
      int e = ebase + n15;
      const float4* vr = (const float4*)(v + (size_t)src[e] * HID);
      int f0 = q * 2;
#pragma unroll
      for (int s = 0; s < 2; ++s) {
        float4 pa = vr[s * 8 + f0], pb = vr[s * 8 + f0 + 1];
        BF8 u;
        u.h[0] = (__bf16)pa.x; u.h[1] = (__bf16)pa.y;
        u.h[2] = (__bf16)pa.z; u.h[3] = (__bf16)pa.w;
        u.h[4] = (__bf16)pb.x; u.h[5] = (__bf16)pb.y;
        u.h[6] = (__bf16)pb.z; u.h[7] = (__bf16)pb.w;
        ubf[s] = u.v;
      }
    }

    f32x4 acc[4];
#pragma unroll
    for (int nt = 0; nt < 4; ++nt) acc[nt] = (f32x4)0.0f;

    int c0 = kchunk * 16;
    const float* hq = h2T_r + (size_t)c0 * EE + ebase + q * 4;
    const int NCC = (kchunk == 3) ? 17 : 16;   // tile 16 = bias row (uniform)

    // stage tile cc into bstage[cc%3]: wave-uniform LDS dest, per-lane global src
    auto stage = [&](int cc) {
      const unsigned short* gt = (cc < 16)
          ? Bt + (size_t)(c0 + cc) * 4096
          : Bt + (size_t)64 * 4096;
      const unsigned short* gsrc = gt + w * 1024 + lane * 8;
      unsigned short* ldst = &bstage[cc % 3][w * 1024];
      gl_lds16(gsrc, ldst);
      gl_lds16(gsrc + 512, ldst + 512);
    };

    stage(0);
    stage(1);

    for (int cc = 0; cc < NCC; ++cc) {
      // stage(cc) complete when <=2 of my loads outstanding (only newer stages)
      asm volatile("s_waitcnt vmcnt(2)" ::: "memory");
      __builtin_amdgcn_s_barrier();
      // h row for THIS tile: issue before the stage so its consumption does
      // not drain the younger stage loads (vmcnt FIFO).
      float4 h4;
      if (cc < 16) h4 = *(const float4*)(hq + (size_t)cc * EE);
      __builtin_amdgcn_sched_barrier(0);
      if (cc + 2 < NCC) stage(cc + 2);
      __builtin_amdgcn_sched_barrier(0);

      const unsigned short* Bs = &bstage[cc % 3][lane * 8];
      bf16x8s bfr[2][4];
#pragma unroll
      for (int s = 0; s < 2; ++s)
#pragma unroll
        for (int nt = 0; nt < 4; ++nt)
          bfr[s][nt] = *(const bf16x8s*)(Bs + (s * 4 + nt) * 512);
      if (cc < 16) {
        f32x4 tmp[4];
#pragma unroll
        for (int nt = 0; nt < 4; ++nt) {
          f32x4 t0 = __builtin_amdgcn_mfma_f32_16x16x32_bf16(
              ubf[0], bfr[0][nt], (f32x4)0.0f, 0, 0, 0);
          tmp[nt] = __builtin_amdgcn_mfma_f32_16x16x32_bf16(
              ubf[1], bfr[1][nt], t0, 0, 0, 0);
        }
#pragma unroll
        for (int nt = 0; nt < 4; ++nt) {
          acc[nt][0] += h4.x * tmp[nt][0];
          acc[nt][1] += h4.y * tmp[nt][1];
          acc[nt][2] += h4.z * tmp[nt][2];
          acc[nt][3] += h4.w * tmp[nt][3];
        }
      } else {
        // bias row c = 64 (h == 1): accumulate directly, A-fragment is ubf
#pragma unroll
        for (int s = 0; s < 2; ++s)
#pragma unroll
          for (int nt = 0; nt < 4; ++nt)
            acc[nt] = __builtin_amdgcn_mfma_f32_16x16x32_bf16(
                ubf[s], bfr[s][nt], acc[nt], 0, 0, 0);
      }
    }

    // epilogue: PLAIN coalesced stores of the per-edge partial
    float* mb = msgbuf + (size_t)kchunk * EE * HID;
#pragma unroll
    for (int r = 0; r < 4; ++r) {
      int e = ebase + q * 4 + r;
#pragma unroll
      for (int nt = 0; nt < 4; ++nt)
        mb[(size_t)e * HID + nt * 16 + n15] = acc[nt][r];
    }
  } else if (b < 1024 + nEm) {
    // ---- edge MLP for NEXT layer, overlapped with MFMA blocks ----
    edgemlp16((b - 1024) * 16, threadIdx.x, ear, meanb, invstd,
              w1, b1, w2, b2, (float*)bstage, h2T_w);
  }
}

// ------- pure update(t): CSR gather over in-edges (no atomics, no aggr) ----------
__global__ __launch_bounds__(256) void k_upd(
    float* __restrict__ v, const float* __restrict__ rw, const float* __restrict__ rb,
    const float* __restrict__ msgbuf, const float* __restrict__ degf,
    const int* __restrict__ rowptr, const int* __restrict__ ecsr) {
  __shared__ float sh[4][HID];
  int g = threadIdx.x >> 6, lane = threadIdx.x & 63;
  int n = blockIdx.x * 4 + g;
  int idx = n * HID + lane;
  sh[g][lane] = v[idx];
  __syncthreads();
  int r0 = rowptr[n], r1 = rowptr[n + 1];
  float s = 0.f;
  for (int j = r0; j < r1; ++j) {
    int e = ecsr[j];
    s += msgbuf[(size_t)e * HID + lane]
       + msgbuf[((size_t)EE + e) * HID + lane]
       + msgbuf[((size_t)2 * EE + e) * HID + lane]
       + msgbuf[((size_t)3 * EE + e) * HID + lane];
  }
  float inv = 1.f / fmaxf(degf[n], 1.f);
  float o = rb[lane] + s * inv;
#pragma unroll
  for (int h = 0; h < HID; ++h) o += sh[g][h] * rw[h * HID + lane];
  v[idx] = fmaxf(o, 0.f);
}

// ------- final layer: update(T-1) + proj fused ----------------------------------
__global__ __launch_bounds__(256) void k_upd_proj(
    const float* __restrict__ v, const float* __restrict__ rw,
    const float* __restrict__ rb,
    const float* __restrict__ msgbuf, const float* __restrict__ degf,
    const int* __restrict__ rowptr, const int* __restrict__ ecsr,
    const float* __restrict__ pw1, const float* __restrict__ pb1,
    const float* __restrict__ pw2, const float* __restrict__ pb2,
    float* __restrict__ out) {
  __shared__ float sh[4][HID];
  int g = threadIdx.x >> 6, lane = threadIdx.x & 63;
  int n = blockIdx.x * 4 + g;
  int idx = n * HID + lane;
  sh[g][lane] = v[idx];
  __syncthreads();
  int r0 = rowptr[n], r1 = rowptr[n + 1];
  float s = 0.f;
  for (int j = r0; j < r1; ++j) {
    int e = ecsr[j];
    s += msgbuf[(size_t)e * HID + lane]
       + msgbuf[((size_t)EE + e) * HID + lane]
       + msgbuf[((size_t)2 * EE + e) * HID + lane]
       + msgbuf[((size_t)3 * EE + e) * HID + lane];
  }
  float inv = 1.f / fmaxf(degf[n], 1.f);
  float o = rb[lane] + s * inv;
#pragma unroll
  for (int h = 0; h < HID; ++h) o += sh[g][h] * rw[h * HID + lane];
  float vn = fmaxf(o, 0.f);
  __syncthreads();
  sh[g][lane] = vn;                       // updated v row
  __syncthreads();
  float a = pb1[lane];
#pragma unroll
  for (int h = 0; h < HID; ++h) a += sh[g][h] * pw1[h * HID + lane];
  float h1 = fmaxf(a, 0.f);
  __syncthreads();
  sh[g][lane] = h1;
  __syncthreads();
  if (lane < OUT_DIM) {
    float oo = pb2[lane];
#pragma unroll
    for (int h = 0; h < HID; ++h) oo += sh[g][h] * pw2[h * OUT_DIM + lane];
    out[n * OUT_DIM + lane] = oo;
  }
}

extern "C" void kernel_launch(void* const* d_in, const int* in_sizes, int n_in,
                              void* d_out, int out_size, void* d_ws, size_t ws_size,
                              hipStream_t stream) {
  const float* x        = (const float*)d_in[0];
  const float* ear      = (const float*)d_in[1];
  const float* lift_w1  = (const float*)d_in[2];
  const float* lift_b1  = (const float*)d_in[3];
  const float* lift_w2  = (const float*)d_in[4];
  const float* lift_b2  = (const float*)d_in[5];
  const float* root_w   = (const float*)d_in[6];
  const float* root_b   = (const float*)d_in[7];
  const float* kw1      = (const float*)d_in[8];
  const float* kb1      = (const float*)d_in[9];
  const float* kw2      = (const float*)d_in[10];
  const float* kb2      = (const float*)d_in[11];
  const float* kw3      = (const float*)d_in[12];
  const float* kb3      = (const float*)d_in[13];
  const float* pw1      = (const float*)d_in[14];
  const float* pb1      = (const float*)d_in[15];
  const float* pw2      = (const float*)d_in[16];
  const float* pb2      = (const float*)d_in[17];
  const int* edge_index = (const int*)d_in[18];
  const int* src = edge_index;
  const int* dst = edge_index + EE;
  float* out = (float*)d_out;

  float* ws     = (float*)d_ws;
  float* msgbuf = ws;                          // 4 * EE * HID  (16.8 MB)
  float* degf   = msgbuf + (size_t)4 * EE * HID;   // NN
  float* h2Ta   = degf + NN;                   // HID*EE (transposed, buf A)
  float* h2Tb   = h2Ta + (size_t)HID * EE;     // HID*EE (buf B)
  float* vbuf   = h2Tb + (size_t)HID * EE;     // NN*HID
  float* meanb  = vbuf + NN * HID;             // 72
  float* invstd = meanb + 72;                  // 72
  unsigned short* Bbf = (unsigned short*)(invstd + 72);  // TT*65*4096 bf16
  int* rowptr = (int*)(Bbf + (size_t)TT * 65 * 4096);    // NN+1
  int* cur    = rowptr + NN + 1;               // NN
  int* ecsr   = cur + NN;                      // EE

  k_stats<<<2 * N_GRAPHS, 256, 0, stream>>>(ear, meanb, invstd, degf);

  const int PRE_BLOCKS = PRE_EM0 + PRE_LIFT + PRE_BPREP + PRE_DEG;
  k_pre<<<PRE_BLOCKS, 256, 0, stream>>>(
      x, lift_w1, lift_b1, lift_w2, lift_b2, vbuf, kw3, kb3, Bbf,
      dst, degf, ear, meanb, invstd,
      kw1, kb1, kw2, kb2, h2Ta);

  k_csr1<<<1, 256, 0, stream>>>(degf, rowptr, cur);
  k_csr2<<<EE / 256, 256, 0, stream>>>(dst, cur, ecsr);

  for (int t = 0; t < TT; ++t) {
    const float* hr = (t & 1) ? h2Tb : h2Ta;
    float*       hw = (t & 1) ? h2Ta : h2Tb;
    int nEm = (t < TT - 1) ? EE / 16 : 0;
    int tt  = (t < TT - 1) ? t + 1 : t;    // em weights for next layer
    k_msg<<<1024 + nEm, 256, 0, stream>>>(
        vbuf, hr, Bbf + (size_t)t * 65 * 4096, src, msgbuf, nEm,
        ear, meanb, invstd,
        kw1 + (size_t)tt * EDGE_DIM * HID, kb1 + (size_t)tt * HID,
        kw2 + (size_t)tt * HID * HID, kb2 + (size_t)tt * HID, hw);
    if (t < TT - 1) {
      k_upd<<<NN / 4, 256, 0, stream>>>(
          vbuf, root_w + (size_t)t * HID * HID, root_b + (size_t)t * HID,
          msgbuf, degf, rowptr, ecsr);
    } else {
      k_upd_proj<<<NN / 4, 256, 0, stream>>>(
          vbuf, root_w + (size_t)t * HID * HID, root_b + (size_t)t * HID,
          msgbuf, degf, rowptr, ecsr, pw1, pb1, pw2, pb2, out);
    }
  }
}